// Round 2
// baseline (77.862 us; speedup 1.0000x reference)
//
#include <hip/hip_runtime.h>

#define NM    20           // nmax
#define NP1   21
#define PTS   16           // points per block
#define BLK   256          // 16 workers per point
#define ROWF  882          // floats per point row = 2*(NM+1)^2
#define BLKF  (PTS * ROWF) // 14112 floats per block
#define BLKF4 (BLKF / 4)   // 3528 float4 per block

struct Tbl {
    float dprod[NP1];      // INV_SQRT_4PI * prod_{k<=m} (-sqrt((2k+1)/(2k)))  (CS phase)
    float e[NP1];          // sqrt(2m+3)
    float a[NP1][NP1];     // recurrence a(m,n)
    float b[NP1][NP1];     // recurrence b(m,n)
};

constexpr double csqrt_d(double x) {
    double r = x * 0.5 + 0.5;
    for (int i = 0; i < 48; ++i) r = 0.5 * (r + x / r);
    return r;
}

constexpr Tbl make_tbl() {
    Tbl t{};
    const double inv4pi = 0.28209479177387814;  // 1/sqrt(4*pi)
    double dp = inv4pi;
    t.dprod[0] = (float)dp;
    for (int m = 1; m <= NM; ++m) {
        dp *= -csqrt_d((2.0 * m + 1.0) / (2.0 * m));
        t.dprod[m] = (float)dp;
    }
    for (int m = 0; m <= NM; ++m) t.e[m] = (float)csqrt_d(2.0 * m + 3.0);
    for (int m = 0; m <= NM; ++m)
        for (int n = m + 2; n <= NM; ++n) {
            double nn = (double)n * n, mm = (double)m * m;
            t.a[m][n] = (float)csqrt_d((4.0 * nn - 1.0) / (nn - mm));
            t.b[m][n] = (float)csqrt_d((2.0 * n + 1.0) * (n - 1.0 - m) * (n - 1.0 + m) /
                                       ((2.0 * n - 3.0) * (nn - mm)));
        }
    return t;
}

__constant__ Tbl TBL = make_tbl();

// Phase 1: workers scatter finished (re,im) channel pairs into an LDS image of
// the block's output region (exact layout). Phase 2: pure float4 LDS->global copy.
__global__ __launch_bounds__(BLK) void sph_kernel(const float* __restrict__ theta,
                                                  const float* __restrict__ phi,
                                                  float* __restrict__ out, int npts) {
    __shared__ __align__(16) float sh[PTS][ROWF];
    const int tid = threadIdx.x;
    const int pt  = tid >> 4;
    const int sub = tid & 15;
    const int gpt0 = blockIdx.x * PTS;
    const int gpt  = gpt0 + pt;

    if (gpt < npts) {
        const float th = theta[gpt];
        const float ph = phi[gpt];
        const float x = cosf(ph);                              // cos(polar)
        const float s = sqrtf(fmaxf(1.0f - x * x, 0.0f));
        float* row = sh[pt];

        auto do_col = [&](int m) {
            float sm_, cm_;
            sincosf((float)m * th, &sm_, &cm_);
            float pmm = TBL.dprod[m];
            for (int k = 0; k < m; ++k) pmm *= s;              // * s^m
            float pb = 0.0f, pa = pmm;
            int nn = m * (m + 1);                              // n*(n+1) at n=m
            for (int n = m; n <= NM; ++n) {
                const float re = pa * cm_, im = pa * sm_;
                *reinterpret_cast<float2*>(row + 2 * (nn + m)) = make_float2(re, im);
                if (m > 0) {
                    // Y_n^{-m}: am odd -> (-re, im); am even -> (re, -im)
                    float2 v = (m & 1) ? make_float2(-re, im) : make_float2(re, -im);
                    *reinterpret_cast<float2*>(row + 2 * (nn - m)) = v;
                }
                if (n < NM) {
                    const float pn = (n == m) ? TBL.e[m] * x * pa
                                              : TBL.a[m][n + 1] * x * pa - TBL.b[m][n + 1] * pb;
                    pb = pa; pa = pn;
                }
                nn += 2 * (n + 1);
            }
        };
        do_col(sub);                 // columns 0..15
        if (sub <= 4) do_col(20 - sub);   // columns 16..20 (balanced: max 22 emits/lane)
    }
    __syncthreads();

    // Phase 2: stream the block's contiguous output image to global.
    const long long base = (long long)blockIdx.x * BLKF;
    if (gpt0 + PTS <= npts) {
        const float4* __restrict__ src = reinterpret_cast<const float4*>(&sh[0][0]);
        float4* __restrict__ dst = reinterpret_cast<float4*>(out + base);
        #pragma unroll
        for (int k = 0; k < BLKF4 / BLK; ++k)                  // 13 full sweeps
            dst[tid + k * BLK] = src[tid + k * BLK];
        const int j = tid + (BLKF4 / BLK) * BLK;               // tail: 3328..3527
        if (j < BLKF4) dst[j] = src[j];
    } else {                                                   // partial last block
        const int vpts = npts - gpt0;
        const float2* __restrict__ src = reinterpret_cast<const float2*>(&sh[0][0]);
        float2* __restrict__ dst = reinterpret_cast<float2*>(out + base);
        for (int j = tid; j < vpts * (ROWF / 2); j += BLK)
            dst[j] = src[j];
    }
}

extern "C" void kernel_launch(void* const* d_in, const int* in_sizes, int n_in,
                              void* d_out, int out_size, void* d_ws, size_t ws_size,
                              hipStream_t stream) {
    const float* theta = (const float*)d_in[0];
    const float* phi   = (const float*)d_in[1];
    float* out = (float*)d_out;
    const int npts = in_sizes[0];
    const int blocks = (npts + PTS - 1) / PTS;
    sph_kernel<<<blocks, BLK, 0, stream>>>(theta, phi, out, npts);
}

// Round 3
// 68.474 us; speedup vs baseline: 1.1371x; 1.1371x over previous
//
#include <hip/hip_runtime.h>

#define NM    20           // nmax
#define NP1   21
#define PTS   4            // points per block
#define BLK   64           // one wave: 4 points x 16 workers
#define ROWF  882          // floats per point row = 2*(NM+1)^2
#define BLKF  (PTS * ROWF) // 3528 floats per block
#define BLKF4 (BLKF / 4)   // 882 float4 per block

struct Tbl {
    float dprod[NP1];      // INV_SQRT_4PI * prod_{k<=m} (-sqrt((2k+1)/(2k)))  (CS phase)
    float e[NP1];          // sqrt(2m+3)
    float a[NP1][NP1];     // recurrence a(m,n)
    float b[NP1][NP1];     // recurrence b(m,n)
};

constexpr double csqrt_d(double x) {
    double r = x * 0.5 + 0.5;
    for (int i = 0; i < 48; ++i) r = 0.5 * (r + x / r);
    return r;
}

constexpr Tbl make_tbl() {
    Tbl t{};
    const double inv4pi = 0.28209479177387814;  // 1/sqrt(4*pi)
    double dp = inv4pi;
    t.dprod[0] = (float)dp;
    for (int m = 1; m <= NM; ++m) {
        dp *= -csqrt_d((2.0 * m + 1.0) / (2.0 * m));
        t.dprod[m] = (float)dp;
    }
    for (int m = 0; m <= NM; ++m) t.e[m] = (float)csqrt_d(2.0 * m + 3.0);
    for (int m = 0; m <= NM; ++m)
        for (int n = m + 2; n <= NM; ++n) {
            double nn = (double)n * n, mm = (double)m * m;
            t.a[m][n] = (float)csqrt_d((4.0 * nn - 1.0) / (nn - mm));
            t.b[m][n] = (float)csqrt_d((2.0 * n + 1.0) * (n - 1.0 - m) * (n - 1.0 + m) /
                                       ((2.0 * n - 3.0) * (nn - mm)));
        }
    return t;
}

__constant__ Tbl TBL = make_tbl();

// One wave per block. Phase 1: 16 workers/point scatter finished (re,im) pairs
// into an LDS image of the block's output region. Phase 2: pure float4 copy.
// Small blocks (14.1KB LDS -> 11 blocks/CU) keep the HBM write stream smooth.
__global__ __launch_bounds__(BLK) void sph_kernel(const float* __restrict__ theta,
                                                  const float* __restrict__ phi,
                                                  float* __restrict__ out, int npts) {
    __shared__ __align__(16) float sh[PTS][ROWF];
    const int tid = threadIdx.x;
    const int pt  = tid >> 4;
    const int sub = tid & 15;
    const int gpt0 = blockIdx.x * PTS;
    const int gpt  = gpt0 + pt;

    if (gpt < npts) {
        const float th = theta[gpt];
        const float ph = phi[gpt];
        const float x = cosf(ph);                              // cos(polar)
        const float s = sqrtf(fmaxf(1.0f - x * x, 0.0f));
        float* row = sh[pt];

        auto do_col = [&](int m) {
            float sm_, cm_;
            sincosf((float)m * th, &sm_, &cm_);
            float pmm = TBL.dprod[m];
            for (int k = 0; k < m; ++k) pmm *= s;              // * s^m
            float pb = 0.0f, pa = pmm;
            int nn = m * (m + 1);                              // n*(n+1) at n=m
            for (int n = m; n <= NM; ++n) {
                const float re = pa * cm_, im = pa * sm_;
                *reinterpret_cast<float2*>(row + 2 * (nn + m)) = make_float2(re, im);
                if (m > 0) {
                    // Y_n^{-m}: am odd -> (-re, im); am even -> (re, -im)
                    float2 v = (m & 1) ? make_float2(-re, im) : make_float2(re, -im);
                    *reinterpret_cast<float2*>(row + 2 * (nn - m)) = v;
                }
                if (n < NM) {
                    const float pn = (n == m) ? TBL.e[m] * x * pa
                                              : TBL.a[m][n + 1] * x * pa - TBL.b[m][n + 1] * pb;
                    pb = pa; pa = pn;
                }
                nn += 2 * (n + 1);
            }
        };
        do_col(sub);                    // columns 0..15
        if (sub <= 4) do_col(20 - sub); // columns 16..20 (max 22 emits/lane)
    }
    __syncthreads();   // single-wave block: compiles to waitcnt, no cross-wave wait

    // Phase 2: stream the block's contiguous output image to global.
    const long long base = (long long)blockIdx.x * BLKF;
    if (gpt0 + PTS <= npts) {
        const float4* __restrict__ src = reinterpret_cast<const float4*>(&sh[0][0]);
        float4* __restrict__ dst = reinterpret_cast<float4*>(out + base);
        #pragma unroll
        for (int k = 0; k < BLKF4 / BLK; ++k)                  // 13 full sweeps
            dst[tid + k * BLK] = src[tid + k * BLK];
        const int j = tid + (BLKF4 / BLK) * BLK;               // tail: 832..881
        if (j < BLKF4) dst[j] = src[j];
    } else {                                                   // partial last block
        const int vpts = npts - gpt0;
        const float2* __restrict__ src = reinterpret_cast<const float2*>(&sh[0][0]);
        float2* __restrict__ dst = reinterpret_cast<float2*>(out + base);
        for (int j = tid; j < vpts * (ROWF / 2); j += BLK)
            dst[j] = src[j];
    }
}

extern "C" void kernel_launch(void* const* d_in, const int* in_sizes, int n_in,
                              void* d_out, int out_size, void* d_ws, size_t ws_size,
                              hipStream_t stream) {
    const float* theta = (const float*)d_in[0];
    const float* phi   = (const float*)d_in[1];
    float* out = (float*)d_out;
    const int npts = in_sizes[0];
    const int blocks = (npts + PTS - 1) / PTS;
    sph_kernel<<<blocks, BLK, 0, stream>>>(theta, phi, out, npts);
}

// Round 5
// 66.023 us; speedup vs baseline: 1.1793x; 1.0371x over previous
//
#include <hip/hip_runtime.h>

#define NM    20           // nmax
#define NP1   21
#define PTS   4            // points per block
#define BLK   64           // one wave: 4 points x 16 workers
#define ROWF  882          // floats per point row = 2*(NM+1)^2
#define BLKF  (PTS * ROWF) // 3528 floats per block
#define BLKF4 (BLKF / 4)   // 882 float4 per block

typedef float f32x4 __attribute__((ext_vector_type(4)));
typedef float f32x2 __attribute__((ext_vector_type(2)));

struct Tbl {
    float dprod[NP1];      // INV_SQRT_4PI * prod_{k<=m} (-sqrt((2k+1)/(2k)))  (CS phase)
    float e[NP1];          // sqrt(2m+3)
    float a[NP1][NP1];     // recurrence a(m,n)
    float b[NP1][NP1];     // recurrence b(m,n)
};

constexpr double csqrt_d(double x) {
    double r = x * 0.5 + 0.5;
    for (int i = 0; i < 48; ++i) r = 0.5 * (r + x / r);
    return r;
}

constexpr Tbl make_tbl() {
    Tbl t{};
    const double inv4pi = 0.28209479177387814;  // 1/sqrt(4*pi)
    double dp = inv4pi;
    t.dprod[0] = (float)dp;
    for (int m = 1; m <= NM; ++m) {
        dp *= -csqrt_d((2.0 * m + 1.0) / (2.0 * m));
        t.dprod[m] = (float)dp;
    }
    for (int m = 0; m <= NM; ++m) t.e[m] = (float)csqrt_d(2.0 * m + 3.0);
    for (int m = 0; m <= NM; ++m)
        for (int n = m + 2; n <= NM; ++n) {
            double nn = (double)n * n, mm = (double)m * m;
            t.a[m][n] = (float)csqrt_d((4.0 * nn - 1.0) / (nn - mm));
            t.b[m][n] = (float)csqrt_d((2.0 * n + 1.0) * (n - 1.0 - m) * (n - 1.0 + m) /
                                       ((2.0 * n - 3.0) * (nn - mm)));
        }
    return t;
}

__constant__ Tbl TBL = make_tbl();

// One wave per block. Phase 1: 16 workers/point scatter finished (re,im) pairs
// into an LDS image of the block's output region. Phase 2: nontemporal float4
// stream to global (bypass L2 write-allocate — the R2 bottleneck theory).
__global__ __launch_bounds__(BLK) void sph_kernel(const float* __restrict__ theta,
                                                  const float* __restrict__ phi,
                                                  float* __restrict__ out, int npts) {
    __shared__ __align__(16) float sh[PTS][ROWF];
    const int tid = threadIdx.x;
    const int pt  = tid >> 4;
    const int sub = tid & 15;
    const int gpt0 = blockIdx.x * PTS;
    const int gpt  = gpt0 + pt;

    if (gpt < npts) {
        const float th = theta[gpt];
        const float ph = phi[gpt];
        const float x = cosf(ph);                              // cos(polar)
        const float s = sqrtf(fmaxf(1.0f - x * x, 0.0f));
        float* row = sh[pt];

        auto do_col = [&](int m) {
            float sm_, cm_;
            sincosf((float)m * th, &sm_, &cm_);
            float pmm = TBL.dprod[m];
            for (int k = 0; k < m; ++k) pmm *= s;              // * s^m
            float pb = 0.0f, pa = pmm;
            int nn = m * (m + 1);                              // n*(n+1) at n=m
            for (int n = m; n <= NM; ++n) {
                const float re = pa * cm_, im = pa * sm_;
                *reinterpret_cast<float2*>(row + 2 * (nn + m)) = make_float2(re, im);
                if (m > 0) {
                    // Y_n^{-m}: am odd -> (-re, im); am even -> (re, -im)
                    float2 v = (m & 1) ? make_float2(-re, im) : make_float2(re, -im);
                    *reinterpret_cast<float2*>(row + 2 * (nn - m)) = v;
                }
                if (n < NM) {
                    const float pn = (n == m) ? TBL.e[m] * x * pa
                                              : TBL.a[m][n + 1] * x * pa - TBL.b[m][n + 1] * pb;
                    pb = pa; pa = pn;
                }
                nn += 2 * (n + 1);
            }
        };
        do_col(sub);                    // columns 0..15
        if (sub <= 4) do_col(20 - sub); // columns 16..20 (max 22 emits/lane)
    }
    __syncthreads();   // single-wave block: compiles to waitcnt

    // Phase 2: nontemporal float4 stream of the block's contiguous output image.
    const long long base = (long long)blockIdx.x * BLKF;
    if (gpt0 + PTS <= npts) {
        const f32x4* __restrict__ src = reinterpret_cast<const f32x4*>(&sh[0][0]);
        f32x4* __restrict__ dst = reinterpret_cast<f32x4*>(out + base);
        #pragma unroll
        for (int k = 0; k < BLKF4 / BLK; ++k)                  // 13 full sweeps
            __builtin_nontemporal_store(src[tid + k * BLK], dst + tid + k * BLK);
        const int j = tid + (BLKF4 / BLK) * BLK;               // tail: 832..881
        if (j < BLKF4) __builtin_nontemporal_store(src[j], dst + j);
    } else {                                                   // partial last block
        const int vpts = npts - gpt0;
        const f32x2* __restrict__ src = reinterpret_cast<const f32x2*>(&sh[0][0]);
        f32x2* __restrict__ dst = reinterpret_cast<f32x2*>(out + base);
        for (int j = tid; j < vpts * (ROWF / 2); j += BLK)
            __builtin_nontemporal_store(src[j], dst + j);
    }
}

extern "C" void kernel_launch(void* const* d_in, const int* in_sizes, int n_in,
                              void* d_out, int out_size, void* d_ws, size_t ws_size,
                              hipStream_t stream) {
    const float* theta = (const float*)d_in[0];
    const float* phi   = (const float*)d_in[1];
    float* out = (float*)d_out;
    const int npts = in_sizes[0];
    const int blocks = (npts + PTS - 1) / PTS;
    sph_kernel<<<blocks, BLK, 0, stream>>>(theta, phi, out, npts);
}